// Round 1
// baseline (5613.446 us; speedup 1.0000x reference)
//
#include <hip/hip_runtime.h>

#define NM 100000
#define NNZE 1600000
#define C 128

__device__ __forceinline__ float sigmoidf_(float x) {
    return 1.0f / (1.0f + __expf(-x));
}

// Y = X @ W   (NM x 128) @ (128 x 128), fp32 vector ALU
__global__ __launch_bounds__(256) void gemm128(const float* __restrict__ X,
                                               const float* __restrict__ W,
                                               float* __restrict__ Y) {
    __shared__ float Ws[128][128];   // 64 KB
    __shared__ float Xs[32][128];    // 16 KB
    int t = threadIdx.x;
    const float4* W4 = (const float4*)W;
    float4* Ws4 = (float4*)&Ws[0][0];
#pragma unroll
    for (int i = 0; i < 16; ++i) Ws4[t + 256 * i] = W4[t + 256 * i];
    long row0 = (long)blockIdx.x * 32;
    const float4* X4 = (const float4*)(X + row0 * C);
    float4* Xs4 = (float4*)&Xs[0][0];
#pragma unroll
    for (int i = 0; i < 4; ++i) Xs4[t + 256 * i] = X4[t + 256 * i];
    __syncthreads();
    int tx = t & 63;          // within-wave lane -> column pair
    int ty = t >> 6;          // wave -> row group (all lanes share rows => LDS broadcast)
    int c0 = tx * 2;
    float acc[8][2] = {};
    for (int k = 0; k < 128; k += 4) {
        float2 w0 = *(const float2*)&Ws[k + 0][c0];
        float2 w1 = *(const float2*)&Ws[k + 1][c0];
        float2 w2 = *(const float2*)&Ws[k + 2][c0];
        float2 w3 = *(const float2*)&Ws[k + 3][c0];
#pragma unroll
        for (int i = 0; i < 8; ++i) {
            float4 xv = *(const float4*)&Xs[ty * 8 + i][k];
            acc[i][0] += xv.x * w0.x + xv.y * w1.x + xv.z * w2.x + xv.w * w3.x;
            acc[i][1] += xv.x * w0.y + xv.y * w1.y + xv.z * w2.y + xv.w * w3.y;
        }
    }
#pragma unroll
    for (int i = 0; i < 8; ++i) {
        long r = row0 + ty * 8 + i;
        *(float2*)&Y[r * C + c0] = make_float2(acc[i][0], acc[i][1]);
    }
}

// h[row] += val * xm[col]  : 32 threads per nnz, float4 per thread
__global__ __launch_bounds__(256) void scatter_add(const int* __restrict__ rows,
                                                   const int* __restrict__ cols,
                                                   const float* __restrict__ vals,
                                                   const float* __restrict__ xm,
                                                   float* h) {
    long tid = (long)blockIdx.x * 256 + threadIdx.x;
    int e = (int)(tid >> 5);
    if (e >= NNZE) return;
    int lane = (int)(tid & 31);
    int r = rows[e];
    int cidx = cols[e];
    float v = vals[e];
    float4 x = ((const float4*)(xm + (long)cidx * C))[lane];
    float* hp = h + (long)r * C + lane * 4;
    atomicAdd(hp + 0, v * x.x);
    atomicAdd(hp + 1, v * x.y);
    atomicAdd(hp + 2, v * x.z);
    atomicAdd(hp + 3, v * x.w);
}

// colsum[c] += sum over rows of h[m][c]
__global__ __launch_bounds__(256) void colsum_kernel(const float* __restrict__ h,
                                                     float* colsum,
                                                     int rows_per_block) {
    __shared__ float tmp[C];
    int c = threadIdx.x & (C - 1);
    int half = threadIdx.x >> 7;
    int m0 = blockIdx.x * rows_per_block;
    int m1 = min(m0 + rows_per_block, NM);
    float acc = 0.0f;
    for (int m = m0 + half; m < m1; m += 2) acc += h[(long)m * C + c];
    if (half) tmp[c] = acc;
    __syncthreads();
    if (!half) atomicAdd(&colsum[c], acc + tmp[c]);
}

// out = sigmoid(0.5*(s1*h1 + s2*h2)) where s_i = sigmoid(relu(sigmoid(colsum_i)) . h_i[m])
// h1 aliases out (read row fully into regs, then overwrite) -- one wave per row
__global__ __launch_bounds__(256) void final_kernel(float* h1out,
                                                    const float* __restrict__ h2,
                                                    const float* __restrict__ cs1,
                                                    const float* __restrict__ cs2) {
    int wave = threadIdx.x >> 6;
    int lane = threadIdx.x & 63;
    long m = (long)blockIdx.x * 4 + wave;
    int c = lane * 2;
    float2 a = *(const float2*)&h1out[m * C + c];
    float2 b = *(const float2*)&h2[m * C + c];
    float w1a = fmaxf(sigmoidf_(cs1[c]), 0.0f);
    float w1b = fmaxf(sigmoidf_(cs1[c + 1]), 0.0f);
    float w2a = fmaxf(sigmoidf_(cs2[c]), 0.0f);
    float w2b = fmaxf(sigmoidf_(cs2[c + 1]), 0.0f);
    float d1 = w1a * a.x + w1b * a.y;
    float d2 = w2a * b.x + w2b * b.y;
#pragma unroll
    for (int off = 32; off; off >>= 1) {
        d1 += __shfl_xor(d1, off);
        d2 += __shfl_xor(d2, off);
    }
    float s1 = sigmoidf_(d1);
    float s2 = sigmoidf_(d2);
    float2 o;
    o.x = sigmoidf_(0.5f * (s1 * a.x + s2 * b.x));
    o.y = sigmoidf_(0.5f * (s1 * a.y + s2 * b.y));
    *(float2*)&h1out[m * C + c] = o;
}

extern "C" void kernel_launch(void* const* d_in, const int* in_sizes, int n_in,
                              void* d_out, int out_size, void* d_ws, size_t ws_size,
                              hipStream_t stream) {
    const float* x1 = (const float*)d_in[0];
    const float* x2 = (const float*)d_in[1];
    const int*   n1r = (const int*)d_in[2];
    const int*   n1c = (const int*)d_in[3];
    const float* n1v = (const float*)d_in[4];
    const int*   n2r = (const int*)d_in[5];
    const int*   n2c = (const int*)d_in[6];
    const float* n2v = (const float*)d_in[7];
    const float* W1 = (const float*)d_in[8];
    const float* W2 = (const float*)d_in[9];

    float* h1 = (float*)d_out;                  // NM*C
    float* ws = (float*)d_ws;
    float* xm = ws;                             // NM*C (reused for both convs)
    float* h2 = ws + (long)NM * C;              // NM*C
    float* cs = ws + 2L * NM * C;               // 256 floats: cs1 | cs2

    hipMemsetAsync(h1, 0, (size_t)NM * C * sizeof(float), stream);
    hipMemsetAsync(h2, 0, (size_t)NM * C * sizeof(float), stream);
    hipMemsetAsync(cs, 0, 256 * sizeof(float), stream);

    const int rpb = (NM + 511) / 512;           // 196

    gemm128<<<NM / 32, 256, 0, stream>>>(x1, W1, xm);
    scatter_add<<<(long)NNZE * 32 / 256, 256, 0, stream>>>(n1r, n1c, n1v, xm, h1);
    colsum_kernel<<<512, 256, 0, stream>>>(h1, cs, rpb);

    gemm128<<<NM / 32, 256, 0, stream>>>(x2, W2, xm);
    scatter_add<<<(long)NNZE * 32 / 256, 256, 0, stream>>>(n2r, n2c, n2v, xm, h2);
    colsum_kernel<<<512, 256, 0, stream>>>(h2, cs + 128, rpb);

    final_kernel<<<NM / 4, 256, 0, stream>>>(h1, h2, cs, cs + 128);
}

// Round 2
// 1029.731 us; speedup vs baseline: 5.4514x; 5.4514x over previous
//
#include <hip/hip_runtime.h>

#define NM 100000
#define NNZE 1600000
#define C 128

typedef unsigned long long u64;

__device__ __forceinline__ float sigmoidf_(float x) {
    return 1.0f / (1.0f + __expf(-x));
}

// Y = X @ W   (NM x 128) @ (128 x 128), fp32 vector ALU
__global__ __launch_bounds__(256) void gemm128(const float* __restrict__ X,
                                               const float* __restrict__ W,
                                               float* __restrict__ Y) {
    __shared__ float Ws[128][128];   // 64 KB
    __shared__ float Xs[32][128];    // 16 KB
    int t = threadIdx.x;
    const float4* W4 = (const float4*)W;
    float4* Ws4 = (float4*)&Ws[0][0];
#pragma unroll
    for (int i = 0; i < 16; ++i) Ws4[t + 256 * i] = W4[t + 256 * i];
    long row0 = (long)blockIdx.x * 32;
    const float4* X4 = (const float4*)(X + row0 * C);
    float4* Xs4 = (float4*)&Xs[0][0];
#pragma unroll
    for (int i = 0; i < 4; ++i) Xs4[t + 256 * i] = X4[t + 256 * i];
    __syncthreads();
    int tx = t & 63;
    int ty = t >> 6;
    int c0 = tx * 2;
    float acc[8][2] = {};
    for (int k = 0; k < 128; k += 4) {
        float2 w0 = *(const float2*)&Ws[k + 0][c0];
        float2 w1 = *(const float2*)&Ws[k + 1][c0];
        float2 w2 = *(const float2*)&Ws[k + 2][c0];
        float2 w3 = *(const float2*)&Ws[k + 3][c0];
#pragma unroll
        for (int i = 0; i < 8; ++i) {
            float4 xv = *(const float4*)&Xs[ty * 8 + i][k];
            acc[i][0] += xv.x * w0.x + xv.y * w1.x + xv.z * w2.x + xv.w * w3.x;
            acc[i][1] += xv.x * w0.y + xv.y * w1.y + xv.z * w2.y + xv.w * w3.y;
        }
    }
#pragma unroll
    for (int i = 0; i < 8; ++i) {
        long r = row0 + ty * 8 + i;
        *(float2*)&Y[r * C + c0] = make_float2(acc[i][0], acc[i][1]);
    }
}

// ---- CSR build ----

__global__ __launch_bounds__(256) void hist_kernel(const int* __restrict__ rows,
                                                   int* __restrict__ cnt) {
    int e = blockIdx.x * 256 + threadIdx.x;
    if (e < NNZE) atomicAdd(&cnt[rows[e]], 1);
}

// single-block exclusive scan of cnt[0..NM) -> off[0..NM]
__global__ __launch_bounds__(1024) void scan_kernel(const int* __restrict__ cnt,
                                                    int* __restrict__ off) {
    __shared__ int wtot[16];
    __shared__ int wexcl[16];
    __shared__ int s_tot;
    int t = threadIdx.x;
    int lane = t & 63;
    int wid = t >> 6;
    int run = 0;
    for (int base = 0; base < NM; base += 1024) {
        int i = base + t;
        int v = (i < NM) ? cnt[i] : 0;
        // wave inclusive scan
        int incl = v;
#pragma unroll
        for (int d = 1; d < 64; d <<= 1) {
            int n = __shfl_up(incl, d);
            if (lane >= d) incl += n;
        }
        if (lane == 63) wtot[wid] = incl;
        __syncthreads();
        if (t < 16) {
            int x = wtot[t];
            int inc = x;
#pragma unroll
            for (int d = 1; d < 16; d <<= 1) {
                int n = __shfl_up(inc, d, 16);
                if (t >= d) inc += n;
            }
            wexcl[t] = inc - x;
            if (t == 15) s_tot = inc;
        }
        __syncthreads();
        if (i < NM) off[i] = run + wexcl[wid] + (incl - v);
        run += s_tot;
        __syncthreads();
    }
    if (t == 0) off[NM] = run;
}

// scatter entries into CSR order; srt[p] = pack(col, val)
__global__ __launch_bounds__(256) void permute_kernel(const int* __restrict__ rows,
                                                      const int* __restrict__ cols,
                                                      const float* __restrict__ vals,
                                                      int* __restrict__ cursor,
                                                      u64* __restrict__ srt) {
    int e = blockIdx.x * 256 + threadIdx.x;
    if (e >= NNZE) return;
    int r = rows[e];
    int p = atomicAdd(&cursor[r], 1);
    u64 pk = (u64)(unsigned)cols[e] | ((u64)__float_as_uint(vals[e]) << 32);
    srt[p] = pk;
}

// h[m] = sum_{i in row m} val_i * xm[col_i]  — one wave per row, no atomics
__global__ __launch_bounds__(256) void spmm_csr(const int* __restrict__ off,
                                                const u64* __restrict__ srt,
                                                const float* __restrict__ xm,
                                                float* __restrict__ h) {
    int wid = threadIdx.x >> 6;
    int lane = threadIdx.x & 63;
    int m = blockIdx.x * 4 + wid;
    int s = off[m], e = off[m + 1];
    int c = lane * 2;
    float2 acc0 = make_float2(0.f, 0.f), acc1 = make_float2(0.f, 0.f);
    int i = s;
    for (; i + 1 < e; i += 2) {
        u64 pk0 = srt[i];
        u64 pk1 = srt[i + 1];
        int c0 = (int)(pk0 & 0xffffffffu);
        int c1 = (int)(pk1 & 0xffffffffu);
        float v0 = __uint_as_float((unsigned)(pk0 >> 32));
        float v1 = __uint_as_float((unsigned)(pk1 >> 32));
        float2 x0 = *(const float2*)&xm[(long)c0 * C + c];
        float2 x1 = *(const float2*)&xm[(long)c1 * C + c];
        acc0.x += v0 * x0.x; acc0.y += v0 * x0.y;
        acc1.x += v1 * x1.x; acc1.y += v1 * x1.y;
    }
    if (i < e) {
        u64 pk0 = srt[i];
        int c0 = (int)(pk0 & 0xffffffffu);
        float v0 = __uint_as_float((unsigned)(pk0 >> 32));
        float2 x0 = *(const float2*)&xm[(long)c0 * C + c];
        acc0.x += v0 * x0.x; acc0.y += v0 * x0.y;
    }
    acc0.x += acc1.x; acc0.y += acc1.y;
    *(float2*)&h[(long)m * C + c] = acc0;
}

// colsum[c] += sum over rows of h[m][c]
__global__ __launch_bounds__(256) void colsum_kernel(const float* __restrict__ h,
                                                     float* colsum,
                                                     int rows_per_block) {
    __shared__ float tmp[C];
    int c = threadIdx.x & (C - 1);
    int half = threadIdx.x >> 7;
    int m0 = blockIdx.x * rows_per_block;
    int m1 = min(m0 + rows_per_block, NM);
    float acc = 0.0f;
    for (int m = m0 + half; m < m1; m += 2) acc += h[(long)m * C + c];
    if (half) tmp[c] = acc;
    __syncthreads();
    if (!half) atomicAdd(&colsum[c], acc + tmp[c]);
}

__global__ __launch_bounds__(256) void final_kernel(float* h1out,
                                                    const float* __restrict__ h2,
                                                    const float* __restrict__ cs1,
                                                    const float* __restrict__ cs2) {
    int wave = threadIdx.x >> 6;
    int lane = threadIdx.x & 63;
    long m = (long)blockIdx.x * 4 + wave;
    int c = lane * 2;
    float2 a = *(const float2*)&h1out[m * C + c];
    float2 b = *(const float2*)&h2[m * C + c];
    float w1a = fmaxf(sigmoidf_(cs1[c]), 0.0f);
    float w1b = fmaxf(sigmoidf_(cs1[c + 1]), 0.0f);
    float w2a = fmaxf(sigmoidf_(cs2[c]), 0.0f);
    float w2b = fmaxf(sigmoidf_(cs2[c + 1]), 0.0f);
    float d1 = w1a * a.x + w1b * a.y;
    float d2 = w2a * b.x + w2b * b.y;
#pragma unroll
    for (int off = 32; off; off >>= 1) {
        d1 += __shfl_xor(d1, off);
        d2 += __shfl_xor(d2, off);
    }
    float s1 = sigmoidf_(d1);
    float s2 = sigmoidf_(d2);
    float2 o;
    o.x = sigmoidf_(0.5f * (s1 * a.x + s2 * b.x));
    o.y = sigmoidf_(0.5f * (s1 * a.y + s2 * b.y));
    *(float2*)&h1out[m * C + c] = o;
}

extern "C" void kernel_launch(void* const* d_in, const int* in_sizes, int n_in,
                              void* d_out, int out_size, void* d_ws, size_t ws_size,
                              hipStream_t stream) {
    const float* x1 = (const float*)d_in[0];
    const float* x2 = (const float*)d_in[1];
    const int*   n1r = (const int*)d_in[2];
    const int*   n1c = (const int*)d_in[3];
    const float* n1v = (const float*)d_in[4];
    const int*   n2r = (const int*)d_in[5];
    const int*   n2c = (const int*)d_in[6];
    const float* n2v = (const float*)d_in[7];
    const float* W1 = (const float*)d_in[8];
    const float* W2 = (const float*)d_in[9];

    float* h1 = (float*)d_out;                     // NM*C
    char* ws = (char*)d_ws;
    size_t o = 0;
    float* xm = (float*)(ws + o);  o += (size_t)NM * C * sizeof(float);   // 51.2MB
    float* h2 = (float*)(ws + o);  o += (size_t)NM * C * sizeof(float);   // 51.2MB
    float* cs = (float*)(ws + o);  o += 256 * sizeof(float);
    int* cnt    = (int*)(ws + o);  o += (size_t)NM * sizeof(int);
    int* off    = (int*)(ws + o);  o += (size_t)(NM + 1) * sizeof(int);
    int* cursor = (int*)(ws + o);  o += (size_t)NM * sizeof(int);
    o = (o + 7) & ~(size_t)7;
    u64* srt    = (u64*)(ws + o);  o += (size_t)NNZE * sizeof(u64);       // 12.8MB

    hipMemsetAsync(cs, 0, 256 * sizeof(float), stream);

    const int rpb = (NM + 511) / 512;              // 196
    const int gE = NNZE / 256;                     // 6250

    // ---- conv1 ----
    gemm128<<<NM / 32, 256, 0, stream>>>(x1, W1, xm);
    hipMemsetAsync(cnt, 0, (size_t)NM * sizeof(int), stream);
    hist_kernel<<<gE, 256, 0, stream>>>(n1r, cnt);
    scan_kernel<<<1, 1024, 0, stream>>>(cnt, off);
    hipMemcpyAsync(cursor, off, (size_t)NM * sizeof(int), hipMemcpyDeviceToDevice, stream);
    permute_kernel<<<gE, 256, 0, stream>>>(n1r, n1c, n1v, cursor, srt);
    spmm_csr<<<NM / 4, 256, 0, stream>>>(off, srt, xm, h1);
    colsum_kernel<<<512, 256, 0, stream>>>(h1, cs, rpb);

    // ---- conv2 ----
    gemm128<<<NM / 32, 256, 0, stream>>>(x2, W2, xm);
    hipMemsetAsync(cnt, 0, (size_t)NM * sizeof(int), stream);
    hist_kernel<<<gE, 256, 0, stream>>>(n2r, cnt);
    scan_kernel<<<1, 1024, 0, stream>>>(cnt, off);
    hipMemcpyAsync(cursor, off, (size_t)NM * sizeof(int), hipMemcpyDeviceToDevice, stream);
    permute_kernel<<<gE, 256, 0, stream>>>(n2r, n2c, n2v, cursor, srt);
    spmm_csr<<<NM / 4, 256, 0, stream>>>(off, srt, xm, h2);
    colsum_kernel<<<512, 256, 0, stream>>>(h2, cs + 128, rpb);

    final_kernel<<<NM / 4, 256, 0, stream>>>(h1, h2, cs, cs + 128);
}

// Round 3
// 837.118 us; speedup vs baseline: 6.7057x; 1.2301x over previous
//
#include <hip/hip_runtime.h>

#define NM 100000
#define NNZE 1600000
#define C 128
#define SCAN_BLK 1024
#define NSCAN ((NM + SCAN_BLK - 1) / SCAN_BLK)   // 98
#define NPASS 4

typedef unsigned long long u64;

__device__ __forceinline__ float sigmoidf_(float x) {
    return 1.0f / (1.0f + __expf(-x));
}

// Y = X @ W   (NM x 128) @ (128 x 128), fp32 vector ALU
__global__ __launch_bounds__(256) void gemm128(const float* __restrict__ X,
                                               const float* __restrict__ W,
                                               float* __restrict__ Y) {
    __shared__ float Ws[128][128];   // 64 KB
    __shared__ float Xs[32][128];    // 16 KB
    int t = threadIdx.x;
    const float4* W4 = (const float4*)W;
    float4* Ws4 = (float4*)&Ws[0][0];
#pragma unroll
    for (int i = 0; i < 16; ++i) Ws4[t + 256 * i] = W4[t + 256 * i];
    long row0 = (long)blockIdx.x * 32;
    const float4* X4 = (const float4*)(X + row0 * C);
    float4* Xs4 = (float4*)&Xs[0][0];
#pragma unroll
    for (int i = 0; i < 4; ++i) Xs4[t + 256 * i] = X4[t + 256 * i];
    __syncthreads();
    int tx = t & 63;
    int ty = t >> 6;
    int c0 = tx * 2;
    float acc[8][2] = {};
    for (int k = 0; k < 128; k += 4) {
        float2 w0 = *(const float2*)&Ws[k + 0][c0];
        float2 w1 = *(const float2*)&Ws[k + 1][c0];
        float2 w2 = *(const float2*)&Ws[k + 2][c0];
        float2 w3 = *(const float2*)&Ws[k + 3][c0];
#pragma unroll
        for (int i = 0; i < 8; ++i) {
            float4 xv = *(const float4*)&Xs[ty * 8 + i][k];
            acc[i][0] += xv.x * w0.x + xv.y * w1.x + xv.z * w2.x + xv.w * w3.x;
            acc[i][1] += xv.x * w0.y + xv.y * w1.y + xv.z * w2.y + xv.w * w3.y;
        }
    }
#pragma unroll
    for (int i = 0; i < 8; ++i) {
        long r = row0 + ty * 8 + i;
        *(float2*)&Y[r * C + c0] = make_float2(acc[i][0], acc[i][1]);
    }
}

// ---- CSR build ----

__global__ __launch_bounds__(256) void hist_kernel(const int* __restrict__ rows,
                                                   int* __restrict__ cnt) {
    int e = blockIdx.x * 256 + threadIdx.x;
    if (e < NNZE) atomicAdd(&cnt[rows[e]], 1);
}

// scan stage 1: per-block local exclusive scan of cnt -> off, block sums -> bsum
__global__ __launch_bounds__(SCAN_BLK) void scan_partial(const int* __restrict__ cnt,
                                                         int* __restrict__ off,
                                                         int* __restrict__ bsum) {
    __shared__ int wtot[16];
    __shared__ int wexcl[16];
    int t = threadIdx.x;
    int lane = t & 63;
    int wid = t >> 6;
    int i = blockIdx.x * SCAN_BLK + t;
    int v = (i < NM) ? cnt[i] : 0;
    int incl = v;
#pragma unroll
    for (int d = 1; d < 64; d <<= 1) {
        int n = __shfl_up(incl, d);
        if (lane >= d) incl += n;
    }
    if (lane == 63) wtot[wid] = incl;
    __syncthreads();
    if (t < 16) {
        int x = wtot[t];
        int inc = x;
#pragma unroll
        for (int d = 1; d < 16; d <<= 1) {
            int n = __shfl_up(inc, d, 16);
            if (t >= d) inc += n;
        }
        wexcl[t] = inc - x;
        if (t == 15) bsum[blockIdx.x] = inc;
    }
    __syncthreads();
    if (i < NM) off[i] = wexcl[wid] + (incl - v);
}

// scan stage 2: exclusive scan of the NSCAN block sums (one small block)
__global__ __launch_bounds__(128) void scan_blocksums(int* __restrict__ bsum,
                                                      int* __restrict__ bbase,
                                                      int* __restrict__ off) {
    __shared__ int wt[2];
    int t = threadIdx.x;
    int lane = t & 63;
    int wid = t >> 6;
    int v = (t < NSCAN) ? bsum[t] : 0;
    int incl = v;
#pragma unroll
    for (int d = 1; d < 64; d <<= 1) {
        int n = __shfl_up(incl, d);
        if (lane >= d) incl += n;
    }
    if (lane == 63) wt[wid] = incl;
    __syncthreads();
    if (wid == 1) incl += wt[0];
    if (t < NSCAN) bbase[t] = incl - v;
    if (t == 127) off[NM] = incl;   // grand total (tail lanes add 0)
}

// scan stage 3: add block bases, emit final off and cursor
__global__ __launch_bounds__(SCAN_BLK) void scan_apply(int* __restrict__ off,
                                                       const int* __restrict__ bbase,
                                                       int* __restrict__ cursor) {
    int i = blockIdx.x * SCAN_BLK + threadIdx.x;
    if (i < NM) {
        int o = off[i] + bbase[blockIdx.x];
        off[i] = o;
        cursor[i] = o;
    }
}

// scatter entries into CSR order, restricted to rows [rlo, rhi) so the
// destination window (~3.2 MB) stays L2-resident; 2 entries/thread for ILP
__global__ __launch_bounds__(256) void permute_pass(const int* __restrict__ rows,
                                                    const int* __restrict__ cols,
                                                    const float* __restrict__ vals,
                                                    int* __restrict__ cursor,
                                                    u64* __restrict__ srt,
                                                    int rlo, int rhi) {
    int e0 = blockIdx.x * 256 + threadIdx.x;
    int e1 = e0 + NNZE / 2;
    int r0 = rows[e0];
    int r1 = rows[e1];
    if (r0 >= rlo && r0 < rhi) {
        int p = atomicAdd(&cursor[r0], 1);
        srt[p] = (u64)(unsigned)cols[e0] | ((u64)__float_as_uint(vals[e0]) << 32);
    }
    if (r1 >= rlo && r1 < rhi) {
        int p = atomicAdd(&cursor[r1], 1);
        srt[p] = (u64)(unsigned)cols[e1] | ((u64)__float_as_uint(vals[e1]) << 32);
    }
}

// h[m] = sum_{i in row m} val_i * xm[col_i]  — one wave per row, no atomics
__global__ __launch_bounds__(256) void spmm_csr(const int* __restrict__ off,
                                                const u64* __restrict__ srt,
                                                const float* __restrict__ xm,
                                                float* __restrict__ h) {
    int wid = threadIdx.x >> 6;
    int lane = threadIdx.x & 63;
    int m = blockIdx.x * 4 + wid;
    int s = off[m], e = off[m + 1];
    int c = lane * 2;
    float2 acc0 = make_float2(0.f, 0.f), acc1 = make_float2(0.f, 0.f);
    int i = s;
    for (; i + 1 < e; i += 2) {
        u64 pk0 = srt[i];
        u64 pk1 = srt[i + 1];
        int c0 = (int)(pk0 & 0xffffffffu);
        int c1 = (int)(pk1 & 0xffffffffu);
        float v0 = __uint_as_float((unsigned)(pk0 >> 32));
        float v1 = __uint_as_float((unsigned)(pk1 >> 32));
        float2 x0 = *(const float2*)&xm[(long)c0 * C + c];
        float2 x1 = *(const float2*)&xm[(long)c1 * C + c];
        acc0.x += v0 * x0.x; acc0.y += v0 * x0.y;
        acc1.x += v1 * x1.x; acc1.y += v1 * x1.y;
    }
    if (i < e) {
        u64 pk0 = srt[i];
        int c0 = (int)(pk0 & 0xffffffffu);
        float v0 = __uint_as_float((unsigned)(pk0 >> 32));
        float2 x0 = *(const float2*)&xm[(long)c0 * C + c];
        acc0.x += v0 * x0.x; acc0.y += v0 * x0.y;
    }
    acc0.x += acc1.x; acc0.y += acc1.y;
    *(float2*)&h[(long)m * C + c] = acc0;
}

// colsum[c] += sum over rows of h[m][c]
__global__ __launch_bounds__(256) void colsum_kernel(const float* __restrict__ h,
                                                     float* colsum,
                                                     int rows_per_block) {
    __shared__ float tmp[C];
    int c = threadIdx.x & (C - 1);
    int half = threadIdx.x >> 7;
    int m0 = blockIdx.x * rows_per_block;
    int m1 = min(m0 + rows_per_block, NM);
    float acc = 0.0f;
    for (int m = m0 + half; m < m1; m += 2) acc += h[(long)m * C + c];
    if (half) tmp[c] = acc;
    __syncthreads();
    if (!half) atomicAdd(&colsum[c], acc + tmp[c]);
}

__global__ __launch_bounds__(256) void final_kernel(float* h1out,
                                                    const float* __restrict__ h2,
                                                    const float* __restrict__ cs1,
                                                    const float* __restrict__ cs2) {
    int wave = threadIdx.x >> 6;
    int lane = threadIdx.x & 63;
    long m = (long)blockIdx.x * 4 + wave;
    int c = lane * 2;
    float2 a = *(const float2*)&h1out[m * C + c];
    float2 b = *(const float2*)&h2[m * C + c];
    float w1a = fmaxf(sigmoidf_(cs1[c]), 0.0f);
    float w1b = fmaxf(sigmoidf_(cs1[c + 1]), 0.0f);
    float w2a = fmaxf(sigmoidf_(cs2[c]), 0.0f);
    float w2b = fmaxf(sigmoidf_(cs2[c + 1]), 0.0f);
    float d1 = w1a * a.x + w1b * a.y;
    float d2 = w2a * b.x + w2b * b.y;
#pragma unroll
    for (int off = 32; off; off >>= 1) {
        d1 += __shfl_xor(d1, off);
        d2 += __shfl_xor(d2, off);
    }
    float s1 = sigmoidf_(d1);
    float s2 = sigmoidf_(d2);
    float2 o;
    o.x = sigmoidf_(0.5f * (s1 * a.x + s2 * b.x));
    o.y = sigmoidf_(0.5f * (s1 * a.y + s2 * b.y));
    *(float2*)&h1out[m * C + c] = o;
}

static void run_conv(const float* x, const float* W,
                     const int* nr, const int* nc, const float* nv,
                     float* xm, float* h, float* cs,
                     int* cnt, int* off, int* cursor, int* bsum, int* bbase,
                     u64* srt, hipStream_t stream) {
    const int rpb = (NM + 511) / 512;              // 196
    const int gE = NNZE / 256;                     // 6250

    gemm128<<<NM / 32, 256, 0, stream>>>(x, W, xm);
    hipMemsetAsync(cnt, 0, (size_t)NM * sizeof(int), stream);
    hist_kernel<<<gE, 256, 0, stream>>>(nr, cnt);
    scan_partial<<<NSCAN, SCAN_BLK, 0, stream>>>(cnt, off, bsum);
    scan_blocksums<<<1, 128, 0, stream>>>(bsum, bbase, off);
    scan_apply<<<NSCAN, SCAN_BLK, 0, stream>>>(off, bbase, cursor);
    for (int p = 0; p < NPASS; ++p) {
        int rlo = p * (NM / NPASS);
        int rhi = (p + 1) * (NM / NPASS);
        permute_pass<<<NNZE / 512, 256, 0, stream>>>(nr, nc, nv, cursor, srt, rlo, rhi);
    }
    spmm_csr<<<NM / 4, 256, 0, stream>>>(off, srt, xm, h);
    colsum_kernel<<<512, 256, 0, stream>>>(h, cs, rpb);
}

extern "C" void kernel_launch(void* const* d_in, const int* in_sizes, int n_in,
                              void* d_out, int out_size, void* d_ws, size_t ws_size,
                              hipStream_t stream) {
    const float* x1 = (const float*)d_in[0];
    const float* x2 = (const float*)d_in[1];
    const int*   n1r = (const int*)d_in[2];
    const int*   n1c = (const int*)d_in[3];
    const float* n1v = (const float*)d_in[4];
    const int*   n2r = (const int*)d_in[5];
    const int*   n2c = (const int*)d_in[6];
    const float* n2v = (const float*)d_in[7];
    const float* W1 = (const float*)d_in[8];
    const float* W2 = (const float*)d_in[9];

    float* h1 = (float*)d_out;                     // NM*C
    char* ws = (char*)d_ws;
    size_t o = 0;
    float* xm = (float*)(ws + o);  o += (size_t)NM * C * sizeof(float);   // 51.2MB
    float* h2 = (float*)(ws + o);  o += (size_t)NM * C * sizeof(float);   // 51.2MB
    float* cs = (float*)(ws + o);  o += 256 * sizeof(float);
    int* cnt    = (int*)(ws + o);  o += (size_t)NM * sizeof(int);
    int* off    = (int*)(ws + o);  o += (size_t)(NM + 1) * sizeof(int);
    int* cursor = (int*)(ws + o);  o += (size_t)NM * sizeof(int);
    int* bsum   = (int*)(ws + o);  o += (size_t)NSCAN * sizeof(int);
    int* bbase  = (int*)(ws + o);  o += (size_t)NSCAN * sizeof(int);
    o = (o + 7) & ~(size_t)7;
    u64* srt    = (u64*)(ws + o);  o += (size_t)NNZE * sizeof(u64);       // 12.8MB

    hipMemsetAsync(cs, 0, 256 * sizeof(float), stream);

    run_conv(x1, W1, n1r, n1c, n1v, xm, h1, cs,       cnt, off, cursor, bsum, bbase, srt, stream);
    run_conv(x2, W2, n2r, n2c, n2v, xm, h2, cs + 128, cnt, off, cursor, bsum, bbase, srt, stream);

    final_kernel<<<NM / 4, 256, 0, stream>>>(h1, h2, cs, cs + 128);
}

// Round 4
// 767.211 us; speedup vs baseline: 7.3167x; 1.0911x over previous
//
#include <hip/hip_runtime.h>

#define NM 100000
#define NNZE 1600000
#define C 128
#define SCAN_BLK 1024
#define NSCAN ((NM + SCAN_BLK - 1) / SCAN_BLK)   // 98
#define NPASS 4

typedef unsigned long long u64;
typedef __attribute__((ext_vector_type(8))) short bf16x8;
typedef __attribute__((ext_vector_type(4))) float f32x4;

__device__ __forceinline__ float sigmoidf_(float x) {
    return 1.0f / (1.0f + __expf(-x));
}
__device__ __forceinline__ short f2bf(float f) {          // fp32 -> bf16 RNE
    unsigned u = __float_as_uint(f);
    return (short)((u + 0x7FFFu + ((u >> 16) & 1u)) >> 16);
}
__device__ __forceinline__ float bf2f(short s) {
    return __uint_as_float(((unsigned)(unsigned short)s) << 16);
}

// Y = X @ W via split-bf16 MFMA: x=xh+xl, W=Wh+Wl, xW ~= xh*Wh + xh*Wl + xl*Wh
// (rel err ~2^-16, so h / colsum stay fp32-accurate). W staged once per block
// in LDS, swizzled so a lane's B-fragment is one ds_read_b128. A-frags loaded
// directly from global (128 B contiguous per row quarter). One wave = 16 rows.
__global__ __launch_bounds__(256) void gemm_mfma(const float* __restrict__ X,
                                                 const float* __restrict__ W,
                                                 float* __restrict__ Y) {
    __shared__ short Whi[16384];   // [kt][ct][lane][j]  4*8*64*8, 32 KB
    __shared__ short Wlo[16384];
    int t = threadIdx.x;
    for (int e = t; e < 16384; e += 256) {
        int k = e >> 7, c = e & 127;
        float w = W[e];
        short hi = f2bf(w);
        short lo = f2bf(w - bf2f(hi));
        int kt = k >> 5, kin = k & 31, ct = c >> 4, cin = c & 15;
        int lane = ((kin >> 3) << 4) | cin;   // B[k][c] held by lane=(kin/8)*16+cin, j=kin&7
        int idx = (((kt << 3) | ct) << 9) + (lane << 3) + (kin & 7);
        Whi[idx] = hi;
        Wlo[idx] = lo;
    }
    __syncthreads();
    int lane = t & 63;
    int wv = t >> 6;
    int gw = blockIdx.x * 4 + wv;            // global wave id (1024 waves)
    int r_lane = lane & 15;                  // A row within tile
    int kg = lane >> 4;                      // k-group 0..3
    const int NT = (NM + 15) / 16;           // 6250 row-tiles
    for (int tile = gw; tile < NT; tile += 1024) {
        int row = tile * 16 + r_lane;
        bool ok = row < NM;
        bf16x8 ahi[4], alo[4];
#pragma unroll
        for (int kt = 0; kt < 4; ++kt) {
            float4 v0 = make_float4(0.f, 0.f, 0.f, 0.f), v1 = v0;
            if (ok) {
                const float4* xp = (const float4*)&X[(long)row * C + kt * 32 + kg * 8];
                v0 = xp[0];
                v1 = xp[1];
            }
            float vv[8] = {v0.x, v0.y, v0.z, v0.w, v1.x, v1.y, v1.z, v1.w};
#pragma unroll
            for (int q = 0; q < 8; ++q) {
                short h = f2bf(vv[q]);
                ahi[kt][q] = h;
                alo[kt][q] = f2bf(vv[q] - bf2f(h));
            }
        }
#pragma unroll
        for (int ct = 0; ct < 8; ++ct) {
            f32x4 acc = {0.f, 0.f, 0.f, 0.f};
#pragma unroll
            for (int kt = 0; kt < 4; ++kt) {
                int bidx = (((kt << 3) | ct) << 9) + (lane << 3);
                bf16x8 bhi = *(bf16x8*)&Whi[bidx];
                bf16x8 blo = *(bf16x8*)&Wlo[bidx];
                acc = __builtin_amdgcn_mfma_f32_16x16x32_bf16(ahi[kt], bhi, acc, 0, 0, 0);
                acc = __builtin_amdgcn_mfma_f32_16x16x32_bf16(ahi[kt], blo, acc, 0, 0, 0);
                acc = __builtin_amdgcn_mfma_f32_16x16x32_bf16(alo[kt], bhi, acc, 0, 0, 0);
            }
            int crow0 = tile * 16 + kg * 4;       // D: row=(lane>>4)*4+r, col=lane&15
            int ccol = ct * 16 + r_lane;
#pragma unroll
            for (int r = 0; r < 4; ++r) {
                int cr = crow0 + r;
                if (cr < NM) Y[(long)cr * C + ccol] = acc[r];
            }
        }
    }
}

// ---- CSR build ----

__global__ __launch_bounds__(256) void hist_kernel(const int* __restrict__ rows,
                                                   int* __restrict__ cnt) {
    int e = blockIdx.x * 256 + threadIdx.x;
    if (e < NNZE) atomicAdd(&cnt[rows[e]], 1);
}

__global__ __launch_bounds__(SCAN_BLK) void scan_partial(const int* __restrict__ cnt,
                                                         int* __restrict__ off,
                                                         int* __restrict__ bsum) {
    __shared__ int wtot[16];
    __shared__ int wexcl[16];
    int t = threadIdx.x;
    int lane = t & 63;
    int wid = t >> 6;
    int i = blockIdx.x * SCAN_BLK + t;
    int v = (i < NM) ? cnt[i] : 0;
    int incl = v;
#pragma unroll
    for (int d = 1; d < 64; d <<= 1) {
        int n = __shfl_up(incl, d);
        if (lane >= d) incl += n;
    }
    if (lane == 63) wtot[wid] = incl;
    __syncthreads();
    if (t < 16) {
        int x = wtot[t];
        int inc = x;
#pragma unroll
        for (int d = 1; d < 16; d <<= 1) {
            int n = __shfl_up(inc, d, 16);
            if (t >= d) inc += n;
        }
        wexcl[t] = inc - x;
        if (t == 15) bsum[blockIdx.x] = inc;
    }
    __syncthreads();
    if (i < NM) off[i] = wexcl[wid] + (incl - v);
}

__global__ __launch_bounds__(128) void scan_blocksums(int* __restrict__ bsum,
                                                      int* __restrict__ bbase,
                                                      int* __restrict__ off) {
    __shared__ int wt[2];
    int t = threadIdx.x;
    int lane = t & 63;
    int wid = t >> 6;
    int v = (t < NSCAN) ? bsum[t] : 0;
    int incl = v;
#pragma unroll
    for (int d = 1; d < 64; d <<= 1) {
        int n = __shfl_up(incl, d);
        if (lane >= d) incl += n;
    }
    if (lane == 63) wt[wid] = incl;
    __syncthreads();
    if (wid == 1) incl += wt[0];
    if (t < NSCAN) bbase[t] = incl - v;
    if (t == 127) off[NM] = incl;
}

__global__ __launch_bounds__(SCAN_BLK) void scan_apply(int* __restrict__ off,
                                                       const int* __restrict__ bbase,
                                                       int* __restrict__ cursor) {
    int i = blockIdx.x * SCAN_BLK + threadIdx.x;
    if (i < NM) {
        int o = off[i] + bbase[blockIdx.x];
        off[i] = o;
        cursor[i] = o;
    }
}

__global__ __launch_bounds__(256) void permute_pass(const int* __restrict__ rows,
                                                    const int* __restrict__ cols,
                                                    const float* __restrict__ vals,
                                                    int* __restrict__ cursor,
                                                    u64* __restrict__ srt,
                                                    int rlo, int rhi) {
    int e0 = blockIdx.x * 256 + threadIdx.x;
    int e1 = e0 + NNZE / 2;
    int r0 = rows[e0];
    int r1 = rows[e1];
    if (r0 >= rlo && r0 < rhi) {
        int p = atomicAdd(&cursor[r0], 1);
        srt[p] = (u64)(unsigned)cols[e0] | ((u64)__float_as_uint(vals[e0]) << 32);
    }
    if (r1 >= rlo && r1 < rhi) {
        int p = atomicAdd(&cursor[r1], 1);
        srt[p] = (u64)(unsigned)cols[e1] | ((u64)__float_as_uint(vals[e1]) << 32);
    }
}

// h[m] = sum val_i * xm[col_i] — one wave/row, unroll-4 for memory-level parallelism
__global__ __launch_bounds__(256) void spmm_csr(const int* __restrict__ off,
                                                const u64* __restrict__ srt,
                                                const float* __restrict__ xm,
                                                float* __restrict__ h) {
    int wid = threadIdx.x >> 6;
    int lane = threadIdx.x & 63;
    int m = blockIdx.x * 4 + wid;
    int s = off[m], e = off[m + 1];
    int c = lane * 2;
    float2 a0 = make_float2(0.f, 0.f), a1 = a0, a2 = a0, a3 = a0;
    int i = s;
    for (; i + 3 < e; i += 4) {
        u64 p0 = srt[i], p1 = srt[i + 1], p2 = srt[i + 2], p3 = srt[i + 3];
        int c0 = (int)(p0 & 0xffffffffu);
        int c1 = (int)(p1 & 0xffffffffu);
        int c2 = (int)(p2 & 0xffffffffu);
        int c3 = (int)(p3 & 0xffffffffu);
        float v0 = __uint_as_float((unsigned)(p0 >> 32));
        float v1 = __uint_as_float((unsigned)(p1 >> 32));
        float v2 = __uint_as_float((unsigned)(p2 >> 32));
        float v3 = __uint_as_float((unsigned)(p3 >> 32));
        float2 x0 = *(const float2*)&xm[(long)c0 * C + c];
        float2 x1 = *(const float2*)&xm[(long)c1 * C + c];
        float2 x2 = *(const float2*)&xm[(long)c2 * C + c];
        float2 x3 = *(const float2*)&xm[(long)c3 * C + c];
        a0.x += v0 * x0.x; a0.y += v0 * x0.y;
        a1.x += v1 * x1.x; a1.y += v1 * x1.y;
        a2.x += v2 * x2.x; a2.y += v2 * x2.y;
        a3.x += v3 * x3.x; a3.y += v3 * x3.y;
    }
    for (; i < e; ++i) {
        u64 p0 = srt[i];
        int c0 = (int)(p0 & 0xffffffffu);
        float v0 = __uint_as_float((unsigned)(p0 >> 32));
        float2 x0 = *(const float2*)&xm[(long)c0 * C + c];
        a0.x += v0 * x0.x; a0.y += v0 * x0.y;
    }
    a0.x += a1.x + a2.x + a3.x;
    a0.y += a1.y + a2.y + a3.y;
    *(float2*)&h[(long)m * C + c] = a0;
}

__global__ __launch_bounds__(256) void colsum_kernel(const float* __restrict__ h,
                                                     float* colsum,
                                                     int rows_per_block) {
    __shared__ float tmp[C];
    int c = threadIdx.x & (C - 1);
    int half = threadIdx.x >> 7;
    int m0 = blockIdx.x * rows_per_block;
    int m1 = min(m0 + rows_per_block, NM);
    float acc = 0.0f;
    for (int m = m0 + half; m < m1; m += 2) acc += h[(long)m * C + c];
    if (half) tmp[c] = acc;
    __syncthreads();
    if (!half) atomicAdd(&colsum[c], acc + tmp[c]);
}

__global__ __launch_bounds__(256) void final_kernel(float* h1out,
                                                    const float* __restrict__ h2,
                                                    const float* __restrict__ cs1,
                                                    const float* __restrict__ cs2) {
    int wave = threadIdx.x >> 6;
    int lane = threadIdx.x & 63;
    long m = (long)blockIdx.x * 4 + wave;
    int c = lane * 2;
    float2 a = *(const float2*)&h1out[m * C + c];
    float2 b = *(const float2*)&h2[m * C + c];
    float w1a = fmaxf(sigmoidf_(cs1[c]), 0.0f);
    float w1b = fmaxf(sigmoidf_(cs1[c + 1]), 0.0f);
    float w2a = fmaxf(sigmoidf_(cs2[c]), 0.0f);
    float w2b = fmaxf(sigmoidf_(cs2[c + 1]), 0.0f);
    float d1 = w1a * a.x + w1b * a.y;
    float d2 = w2a * b.x + w2b * b.y;
#pragma unroll
    for (int off = 32; off; off >>= 1) {
        d1 += __shfl_xor(d1, off);
        d2 += __shfl_xor(d2, off);
    }
    float s1 = sigmoidf_(d1);
    float s2 = sigmoidf_(d2);
    float2 o;
    o.x = sigmoidf_(0.5f * (s1 * a.x + s2 * b.x));
    o.y = sigmoidf_(0.5f * (s1 * a.y + s2 * b.y));
    *(float2*)&h1out[m * C + c] = o;
}

static void run_conv(const float* x, const float* W,
                     const int* nr, const int* nc, const float* nv,
                     float* xm, float* h, float* cs,
                     int* cnt, int* off, int* cursor, int* bsum, int* bbase,
                     u64* srt, hipStream_t stream) {
    const int rpb = (NM + 511) / 512;              // 196
    const int gE = NNZE / 256;                     // 6250

    gemm_mfma<<<256, 256, 0, stream>>>(x, W, xm);
    hipMemsetAsync(cnt, 0, (size_t)NM * sizeof(int), stream);
    hist_kernel<<<gE, 256, 0, stream>>>(nr, cnt);
    scan_partial<<<NSCAN, SCAN_BLK, 0, stream>>>(cnt, off, bsum);
    scan_blocksums<<<1, 128, 0, stream>>>(bsum, bbase, off);
    scan_apply<<<NSCAN, SCAN_BLK, 0, stream>>>(off, bbase, cursor);
    for (int p = 0; p < NPASS; ++p) {
        int rlo = p * (NM / NPASS);
        int rhi = (p + 1) * (NM / NPASS);
        permute_pass<<<NNZE / 512, 256, 0, stream>>>(nr, nc, nv, cursor, srt, rlo, rhi);
    }
    spmm_csr<<<NM / 4, 256, 0, stream>>>(off, srt, xm, h);
    colsum_kernel<<<512, 256, 0, stream>>>(h, cs, rpb);
}

extern "C" void kernel_launch(void* const* d_in, const int* in_sizes, int n_in,
                              void* d_out, int out_size, void* d_ws, size_t ws_size,
                              hipStream_t stream) {
    const float* x1 = (const float*)d_in[0];
    const float* x2 = (const float*)d_in[1];
    const int*   n1r = (const int*)d_in[2];
    const int*   n1c = (const int*)d_in[3];
    const float* n1v = (const float*)d_in[4];
    const int*   n2r = (const int*)d_in[5];
    const int*   n2c = (const int*)d_in[6];
    const float* n2v = (const float*)d_in[7];
    const float* W1 = (const float*)d_in[8];
    const float* W2 = (const float*)d_in[9];

    float* h1 = (float*)d_out;                     // NM*C
    char* ws = (char*)d_ws;
    size_t o = 0;
    float* xm = (float*)(ws + o);  o += (size_t)NM * C * sizeof(float);   // 51.2MB
    float* h2 = (float*)(ws + o);  o += (size_t)NM * C * sizeof(float);   // 51.2MB
    float* cs = (float*)(ws + o);  o += 256 * sizeof(float);
    int* cnt    = (int*)(ws + o);  o += (size_t)NM * sizeof(int);
    int* off    = (int*)(ws + o);  o += (size_t)(NM + 1) * sizeof(int);
    int* cursor = (int*)(ws + o);  o += (size_t)NM * sizeof(int);
    int* bsum   = (int*)(ws + o);  o += (size_t)NSCAN * sizeof(int);
    int* bbase  = (int*)(ws + o);  o += (size_t)NSCAN * sizeof(int);
    o = (o + 7) & ~(size_t)7;
    u64* srt    = (u64*)(ws + o);  o += (size_t)NNZE * sizeof(u64);       // 12.8MB

    hipMemsetAsync(cs, 0, 256 * sizeof(float), stream);

    run_conv(x1, W1, n1r, n1c, n1v, xm, h1, cs,       cnt, off, cursor, bsum, bbase, srt, stream);
    run_conv(x2, W2, n2r, n2c, n2v, xm, h2, cs + 128, cnt, off, cursor, bsum, bbase, srt, stream);

    final_kernel<<<NM / 4, 256, 0, stream>>>(h1, h2, cs, cs + 128);
}